// Round 9
// baseline (5208.381 us; speedup 1.0000x reference)
//
#include <hip/hip_runtime.h>
#include <hip/hip_bf16.h>

#define T 4096
#define BT (16*4096)
#define NL 20
#define TPB 4608   // 512 pad + 4096 tokens per batch
#define PAD 512

typedef __bf16 bf16;
typedef __bf16 v8bf __attribute__((ext_vector_type(8)));
typedef float v4f __attribute__((ext_vector_type(4)));
typedef unsigned int uint32;
typedef unsigned short ushort16;

#define MFMA(a,b,c) __builtin_amdgcn_mfma_f32_16x16x32_bf16((a),(b),(c),0,0,0)

__device__ __forceinline__ int swz512(int row, int bc)  { return row*512  + (bc ^ ((row&7)<<4)); }

__device__ __forceinline__ ushort16 bfbits(float v) {
    bf16 h = (bf16)v; return *(ushort16*)&h;
}
__device__ __forceinline__ uint32 pack2(float zf, float sf) {
    return (uint32)bfbits(zf) | ((uint32)bfbits(sf) << 16);
}
__device__ __forceinline__ float lo_f(uint32 v) { uint32 t = v << 16;          return *(float*)&t; }
__device__ __forceinline__ float hi_f(uint32 v) { uint32 t = v & 0xffff0000u;  return *(float*)&t; }
__device__ __forceinline__ float sel_f(uint32 pair, int j) {  // j&1: 0=lo,1=hi
    uint32 t = (j & 1) ? (pair & 0xffff0000u) : (pair << 16);
    return *(float*)&t;
}
__device__ __forceinline__ float tanh_clamped(float fv) {
    fv = fminf(fmaxf(fv, -20.f), 20.f);
    float e2 = __expf(-2.f * fv);
    return (1.f - e2) / (1.f + e2);
}
__device__ __forceinline__ float sigmoidf_(float v) {
    return 1.f / (1.f + __expf(-v));
}

// ---------------- zero the per-batch pad stripes of both zn buffers ----------------
__global__ void zero_pads(bf16* __restrict__ zn_a, bf16* __restrict__ zn_b) {
    int idx = blockIdx.x * 256 + threadIdx.x;      // 2*16*16384 uint4
    int buf = idx >> 18;
    int r = idx & 262143;
    int b = r >> 14, off = r & 16383;              // pad = 512 rows * 32 uint4
    bf16* base = buf ? zn_b : zn_a;
    ((uint4*)(base + (size_t)b * TPB * 256))[off] = make_uint4(0, 0, 0, 0);
}

// ---------------- prep kernels: cast/reorder weights to bf16 ----------------
__global__ void prep_w2(const float* __restrict__ Wf, const float* __restrict__ Wg,
                        bf16* __restrict__ wf0, bf16* __restrict__ wf1,
                        bf16* __restrict__ wg0, bf16* __restrict__ wg1) {
    int idx = blockIdx.x * 256 + threadIdx.x;       // NL*256*256
    const float* pf = Wf + (size_t)idx * 2;
    wf0[idx] = (bf16)pf[0]; wf1[idx] = (bf16)pf[1];
    const float* pg = Wg + (size_t)idx * 2;
    wg0[idx] = (bf16)pg[0]; wg1[idx] = (bf16)pg[1];
}

__global__ void prep_w1(const float* __restrict__ Wr, const float* __restrict__ Ws,
                        bf16* __restrict__ wr, bf16* __restrict__ ws) {
    int idx = blockIdx.x * 256 + threadIdx.x;       // NL*256*256
    wr[idx] = (bf16)Wr[idx]; ws[idx] = (bf16)Ws[idx];
}

__global__ void prep_misc(const float* __restrict__ W_in, const float* __restrict__ W1,
                          const float* __restrict__ W2,
                          bf16* __restrict__ winb, bf16* __restrict__ w1b, bf16* __restrict__ w2b) {
    int idx = blockIdx.x * 256 + threadIdx.x;       // 458752 total
    if (idx < 65536) {
        int c = idx >> 8, jj = idx & 255, k = jj >> 3, ci = jj & 7;
        winb[idx] = (bf16)W_in[c * 256 + ci * 32 + k];   // winb[c][k*8+ci]
    } else if (idx < 327680) {
        int j = idx - 65536; w1b[j] = (bf16)W1[j];
    } else {
        int j = idx - 327680; w2b[j] = (bf16)W2[j];
    }
}

// ---------------- fused input conv + RMSNorm(norm_w[0]) ----------------
// 8 waves; wave w owns all 64 rows x cols [w*32, w*32+32)
__global__ __launch_bounds__(512, 4) void in_conv_kernel(
    const float* __restrict__ x, const bf16* __restrict__ winb,
    const float* __restrict__ b_in, const float* __restrict__ nw0,
    uint32* __restrict__ zsb, bf16* __restrict__ znout) {
    __shared__ __align__(16) char smem[65536];
    char* cW  = smem + 32768;                 // window tile
    char* cZn = smem;                         // zn staging
    float* rsq = (float*)(smem + 32768);      // alias cW after GEMM reads
    const int tid = threadIdx.x;
    const int g0 = blockIdx.x * 64;
    const int tl0 = g0 & (T - 1);
    const size_t pr0 = (size_t)(g0 >> 12) * TPB + PAD + tl0;
    for (int i = 0; i < 4; ++i) {
        int ch = tid + i * 512;
        int r = ch >> 5, c16 = ch & 31;
        int tok = tl0 + r - 31 + c16;
        bf16 t8[8] = {};
        if (tok >= 0) {
            const float* xr = x + (size_t)(g0 + r - 31 + c16) * 8;
            float4 xa = ((const float4*)xr)[0];
            float4 xb4 = ((const float4*)xr)[1];
            t8[0]=(bf16)xa.x; t8[1]=(bf16)xa.y; t8[2]=(bf16)xa.z; t8[3]=(bf16)xa.w;
            t8[4]=(bf16)xb4.x; t8[5]=(bf16)xb4.y; t8[6]=(bf16)xb4.z; t8[7]=(bf16)xb4.w;
        }
        *(uint4*)(cW + swz512(r, c16 * 16)) = *(uint4*)t8;
    }
    __syncthreads();
    const int lane = tid & 63, w = tid >> 6;
    const int wn = w;
    const int l15 = lane & 15, l4 = lane >> 4;
    const int cbase = wn * 32 + l15;
    uint32* zb_t = zsb + ((size_t)blockIdx.x * 512 + tid) * 32;

    float p8[4][4] = {};
    uint32 zpk[2][4][2] = {};
    #pragma unroll
    for (int half = 0; half < 2; ++half) {
        v4f acc[4] = {};
        __builtin_amdgcn_s_setprio(1);
        #pragma unroll
        for (int ks = 0; ks < 8; ++ks) {
            v8bf b = *(const v8bf*)(winb + (size_t)(cbase + half*16)*256 + ks*32 + l4*8);
            #pragma unroll
            for (int m = 0; m < 4; ++m) {
                v8bf a = *(const v8bf*)(cW + swz512(m*16 + l15, ks*64 + l4*16));
                acc[m] = MFMA(a, b, acc[m]);
            }
        }
        __builtin_amdgcn_s_setprio(0);
        float bv = b_in[cbase + half*16];
        #pragma unroll
        for (int m = 0; m < 4; ++m) {
            uint32 st[4];
            #pragma unroll
            for (int j = 0; j < 4; ++j) {
                float zf = acc[m][j] + bv;
                st[j] = pack2(zf, 0.f);
                p8[m][j] += zf * zf;
                zpk[half][m][j>>1] |= (uint32)bfbits(zf) << ((j&1)*16);
            }
            *(uint4*)(zb_t + half*16 + m*4) = make_uint4(st[0], st[1], st[2], st[3]);
        }
    }
    __syncthreads();                                  // window reads done
    #pragma unroll
    for (int m = 0; m < 4; ++m)
        #pragma unroll
        for (int j = 0; j < 4; ++j) {
            float p = p8[m][j];
            p += __shfl_xor(p,1); p += __shfl_xor(p,2); p += __shfl_xor(p,4); p += __shfl_xor(p,8);
            if (l15 == 0) rsq[(m*16 + l4*4 + j)*9 + wn] = p;
        }
    __syncthreads();                                  // rsq ready
    #pragma unroll
    for (int m = 0; m < 4; ++m)
        #pragma unroll
        for (int j = 0; j < 4; ++j) {
            int row = m*16 + l4*4 + j;
            const float* rr = rsq + row*9;
            float s8 = rr[0]+rr[1]+rr[2]+rr[3]+rr[4]+rr[5]+rr[6]+rr[7];
            float iv = rsqrtf(s8*(1.f/256.f) + 1e-6f);
            #pragma unroll
            for (int half = 0; half < 2; ++half) {
                int col = cbase + half*16;
                float zf = sel_f(zpk[half][m][j>>1], j);
                *(bf16*)(cZn + swz512(row, col*2)) = (bf16)(zf * iv * nw0[col]);
            }
        }
    __syncthreads();
    #pragma unroll
    for (int k = 0; k < 4; ++k) {
        int idx = tid + k * 512;
        int row = idx >> 5, d = idx & 31;
        uint4 v = *(uint4*)(cZn + swz512(row, d*16));
        *((uint4*)(znout + (pr0 + row) * 256) + d) = v;
    }
}

// ---------------- fused gated-residual layer + next-layer RMSNorm ----------------
// wave w owns all 64 rows x cols [w*32, w*32+32). mode: 1=normal, 2=last
// A operands (zn[t], zn[t-dil]) read DIRECTLY from global (L1/L2 cached, 8x wave reuse).
// LDS holds only the U tile (32KB) + rsq; zn-out staging reuses the U region.
__global__ __launch_bounds__(512, 4) void layer_kernel(
    const bf16* __restrict__ znin, bf16* __restrict__ znout, uint32* __restrict__ zsb,
    const bf16* __restrict__ wf0, const bf16* __restrict__ wf1,
    const bf16* __restrict__ wg0, const bf16* __restrict__ wg1,
    const bf16* __restrict__ wr, const bf16* __restrict__ wsm,
    const float* __restrict__ bfp, const float* __restrict__ bgp,
    const float* __restrict__ brp, const float* __restrict__ bsp,
    const float* __restrict__ nw, int dil, int mode) {
    __shared__ __align__(16) char smem[35072];
    char* cU = smem;                      // U tile -> zn-out staging
    float* rsq = (float*)(smem + 32768);
    const int tid = threadIdx.x;
    const int lane = tid & 63, w = tid >> 6;
    const int g0 = blockIdx.x * 64;
    const size_t pr0 = (size_t)(g0 >> 12) * TPB + PAD + (g0 & (T - 1));

    const int wn = w;
    const int l15 = lane & 15, l4 = lane >> 4;
    const int cbase = wn * 32 + l15;
    uint32* zb_t = zsb + ((size_t)blockIdx.x * 512 + tid) * 32;

    // per-lane A base pointers (t and t-dil)
    const bf16* at = znin + (pr0 + l15) * 256 + l4 * 8;
    const bf16* ad = at - (size_t)dil * 256;

    // prefetch zsb old (half 0) — latency hides under GEMM1
    uint4 old0[4];
    #pragma unroll
    for (int m = 0; m < 4; ++m) old0[m] = *(const uint4*)(zb_t + m*4);

    // ---- GEMM1: f+g combined, per 16-col half; A direct from global ----
    uint32 upk[2][4][2];                           // [half][m][jpair] packed bf16 u
    #pragma unroll
    for (int half = 0; half < 2; ++half) {
        v4f accf[4] = {}, accg[4] = {};
        __builtin_amdgcn_s_setprio(1);
        #pragma unroll
        for (int ks = 0; ks < 8; ++ks) {
            size_t bo = (size_t)(cbase + half*16) * 256 + ks*32 + l4*8;
            v8bf bf0 = *(const v8bf*)(wf0 + bo);
            v8bf bf1 = *(const v8bf*)(wf1 + bo);
            v8bf bg0 = *(const v8bf*)(wg0 + bo);
            v8bf bg1 = *(const v8bf*)(wg1 + bo);
            #pragma unroll
            for (int m = 0; m < 4; ++m) {
                v8bf a0 = *(const v8bf*)(ad + m*16*256 + ks*32);
                v8bf a1 = *(const v8bf*)(at + m*16*256 + ks*32);
                accf[m] = MFMA(a0, bf0, accf[m]);
                accf[m] = MFMA(a1, bf1, accf[m]);
                accg[m] = MFMA(a0, bg0, accg[m]);
                accg[m] = MFMA(a1, bg1, accg[m]);
            }
        }
        __builtin_amdgcn_s_setprio(0);
        float bfv = bfp[cbase + half*16];
        float bgv = bgp[cbase + half*16];
        #pragma unroll
        for (int m = 0; m < 4; ++m)
            #pragma unroll
            for (int jp = 0; jp < 2; ++jp) {
                float u0 = tanh_clamped(accf[m][jp*2]   + bfv) * sigmoidf_(accg[m][jp*2]   + bgv);
                float u1 = tanh_clamped(accf[m][jp*2+1] + bfv) * sigmoidf_(accg[m][jp*2+1] + bgv);
                upk[half][m][jp] = (uint32)bfbits(u0) | ((uint32)bfbits(u1) << 16);
            }
    }

    // prefetch zsb old (half 1)
    uint4 old1[4];
    #pragma unroll
    for (int m = 0; m < 4; ++m) old1[m] = *(const uint4*)(zb_t + 16 + m*4);

    // write U tile (bf16, swizzled) into cU
    #pragma unroll
    for (int half = 0; half < 2; ++half)
        #pragma unroll
        for (int m = 0; m < 4; ++m) {
            int col = cbase + half*16;
            #pragma unroll
            for (int j = 0; j < 4; ++j) {
                int row = m*16 + l4*4 + j;
                *(bf16*)(cU + swz512(row, col*2)) = (bf16)sel_f(upk[half][m][j>>1], j);
            }
        }
    __syncthreads();                               // S1: U visible to all waves

    // ---- GEMM2 per half with blocked zs RMW ----
    float p8[4][4] = {};
    uint32 zpk[2][4][2] = {};
    #pragma unroll
    for (int half = 0; half < 2; ++half) {
        uint32 old_[4][4];
        #pragma unroll
        for (int m = 0; m < 4; ++m) {
            uint4 o4 = half ? old1[m] : old0[m];
            old_[m][0] = o4.x; old_[m][1] = o4.y; old_[m][2] = o4.z; old_[m][3] = o4.w;
        }
        v4f accr[4] = {}, accs[4] = {};
        if (mode != 2) {
            __builtin_amdgcn_s_setprio(1);
            #pragma unroll
            for (int ks = 0; ks < 8; ++ks) {
                size_t bo = (size_t)(cbase + half*16) * 256 + ks*32 + l4*8;
                v8bf br_ = *(const v8bf*)(wr + bo);
                v8bf bs_ = *(const v8bf*)(wsm + bo);
                #pragma unroll
                for (int m = 0; m < 4; ++m) {
                    v8bf a = *(const v8bf*)(cU + swz512(m*16 + l15, ks*64 + l4*16));
                    accr[m] = MFMA(a, br_, accr[m]);
                    accs[m] = MFMA(a, bs_, accs[m]);
                }
            }
            __builtin_amdgcn_s_setprio(0);
        } else {
            __builtin_amdgcn_s_setprio(1);
            #pragma unroll
            for (int ks = 0; ks < 8; ++ks) {
                size_t bo = (size_t)(cbase + half*16) * 256 + ks*32 + l4*8;
                v8bf bs_ = *(const v8bf*)(wsm + bo);
                #pragma unroll
                for (int m = 0; m < 4; ++m) {
                    v8bf a = *(const v8bf*)(cU + swz512(m*16 + l15, ks*64 + l4*16));
                    accs[m] = MFMA(a, bs_, accs[m]);
                }
            }
            __builtin_amdgcn_s_setprio(0);
        }
        if (mode != 2) {
            float brv = brp[cbase + half*16];
            float bsv = bsp[cbase + half*16];
            #pragma unroll
            for (int m = 0; m < 4; ++m) {
                uint32 st[4];
                #pragma unroll
                for (int j = 0; j < 4; ++j) {
                    float zf = lo_f(old_[m][j]) + accr[m][j] + brv;
                    float sf = hi_f(old_[m][j]) + accs[m][j] + bsv;
                    st[j] = pack2(zf, sf);
                    p8[m][j] += zf * zf;
                    zpk[half][m][j>>1] |= (uint32)bfbits(zf) << ((j&1)*16);
                }
                *(uint4*)(zb_t + half*16 + m*4) = make_uint4(st[0], st[1], st[2], st[3]);
            }
        } else {
            float bsv = bsp[cbase + half*16];
            #pragma unroll
            for (int m = 0; m < 4; ++m)
                #pragma unroll
                for (int j = 0; j < 4; ++j) {
                    float of = fmaxf(hi_f(old_[m][j]) + accs[m][j] + bsv, 0.f);
                    p8[m][j] += of * of;
                    zpk[half][m][j>>1] |= (uint32)bfbits(of) << ((j&1)*16);
                }
        }
    }
    #pragma unroll
    for (int m = 0; m < 4; ++m)
        #pragma unroll
        for (int j = 0; j < 4; ++j) {
            float p = p8[m][j];
            p += __shfl_xor(p,1); p += __shfl_xor(p,2); p += __shfl_xor(p,4); p += __shfl_xor(p,8);
            if (l15 == 0) rsq[(m*16 + l4*4 + j)*9 + wn] = p;
        }
    __syncthreads();                               // S2: GEMM2 U-reads + rsq done

    // zn staging (bf16, swizzled) into cU region
    #pragma unroll
    for (int m = 0; m < 4; ++m)
        #pragma unroll
        for (int j = 0; j < 4; ++j) {
            int row = m*16 + l4*4 + j;
            const float* rr = rsq + row*9;
            float s8 = rr[0]+rr[1]+rr[2]+rr[3]+rr[4]+rr[5]+rr[6]+rr[7];
            float iv = rsqrtf(s8*(1.f/256.f) + 1e-6f);
            #pragma unroll
            for (int half = 0; half < 2; ++half) {
                int col = cbase + half*16;
                float zf = sel_f(zpk[half][m][j>>1], j);
                *(bf16*)(cU + swz512(row, col*2)) = (bf16)(zf * iv * nw[col]);
            }
        }
    __syncthreads();                               // S3

    // coalesced zn copyout (padded layout)
    #pragma unroll
    for (int k = 0; k < 4; ++k) {
        int idx = tid + k * 512;
        int row = idx >> 5, d = idx & 31;
        uint4 v = *(uint4*)(cU + swz512(row, d*16));
        *((uint4*)(znout + (pr0 + row) * 256) + d) = v;
    }
}

// ---------------- fused head: on @ W1 -> relu -> @ W2 (8 waves) ----------------
// A (on tile) direct from global; only H tile in LDS.
__global__ __launch_bounds__(512, 4) void head_kernel(
    const bf16* __restrict__ on, const bf16* __restrict__ w1b, const float* __restrict__ b1,
    const bf16* __restrict__ w2b, const float* __restrict__ b2, float* __restrict__ out) {
    __shared__ __align__(16) char smem[32768];
    char* cH  = smem;
    const int tid = threadIdx.x;
    const int g0 = blockIdx.x * 64;
    const size_t pr0 = (size_t)(g0 >> 12) * TPB + PAD + (g0 & (T - 1));
    const int lane = tid & 63, w = tid >> 6;
    const int wm = w >> 2, wn = w & 3;
    const int l15 = lane & 15, l4 = lane >> 4;
    const int r0 = wm * 32;
    const bf16* aon = on + (pr0 + r0 + l15) * 256 + l4 * 8;
    v4f acc2[2][2] = {};
    for (int hc = 0; hc < 4; ++hc) {
        v4f acch[2][4] = {};
        __builtin_amdgcn_s_setprio(1);
        #pragma unroll
        for (int ks = 0; ks < 8; ++ks) {
            v8bf a[2];
            #pragma unroll
            for (int m = 0; m < 2; ++m)
                a[m] = *(const v8bf*)(aon + m*16*256 + ks*32);
            #pragma unroll
            for (int nf = 0; nf < 4; ++nf) {
                int h = hc * 256 + wn * 64 + nf * 16 + l15;
                v8bf b = *(const v8bf*)(w1b + (size_t)h * 256 + ks * 32 + l4 * 8);
                #pragma unroll
                for (int m = 0; m < 2; ++m) acch[m][nf] = MFMA(a[m], b, acch[m][nf]);
            }
        }
        __builtin_amdgcn_s_setprio(0);
        __syncthreads();   // previous hc's cH reads done
        #pragma unroll
        for (int m = 0; m < 2; ++m)
            #pragma unroll
            for (int nf = 0; nf < 4; ++nf) {
                int coll = wn * 64 + nf * 16 + l15;
                float b1v = b1[hc * 256 + coll];
                #pragma unroll
                for (int j = 0; j < 4; ++j) {
                    int row = r0 + m*16 + l4*4 + j;
                    float hv = fmaxf(acch[m][nf][j] + b1v, 0.f);
                    *(bf16*)(cH + swz512(row, coll * 2)) = (bf16)hv;
                }
            }
        __syncthreads();
        __builtin_amdgcn_s_setprio(1);
        #pragma unroll
        for (int ks = 0; ks < 8; ++ks) {
            v8bf a[2];
            #pragma unroll
            for (int m = 0; m < 2; ++m)
                a[m] = *(const v8bf*)(cH + swz512(r0 + m*16 + l15, ks*64 + l4*16));
            #pragma unroll
            for (int nf = 0; nf < 2; ++nf) {
                int o = wn * 32 + nf * 16 + l15;
                v8bf b = *(const v8bf*)(w2b + (size_t)o * 1024 + hc * 256 + ks * 32 + l4 * 8);
                #pragma unroll
                for (int m = 0; m < 2; ++m) acc2[m][nf] = MFMA(a[m], b, acc2[m][nf]);
            }
        }
        __builtin_amdgcn_s_setprio(0);
    }
    #pragma unroll
    for (int m = 0; m < 2; ++m)
        #pragma unroll
        for (int nf = 0; nf < 2; ++nf) {
            int o = wn * 32 + nf * 16 + l15;
            float b2v = b2[o];
            #pragma unroll
            for (int j = 0; j < 4; ++j) {
                int row = r0 + m*16 + l4*4 + j;
                out[(size_t)(g0 + row) * 128 + o] = acc2[m][nf][j] + b2v;
            }
        }
}

extern "C" void kernel_launch(void* const* d_in, const int* in_sizes, int n_in,
                              void* d_out, int out_size, void* d_ws, size_t ws_size,
                              hipStream_t stream) {
    const float* x      = (const float*)d_in[0];
    const float* W_in   = (const float*)d_in[1];
    const float* b_in   = (const float*)d_in[2];
    const float* W_f    = (const float*)d_in[3];
    const float* b_f    = (const float*)d_in[4];
    const float* W_g    = (const float*)d_in[5];
    const float* b_g    = (const float*)d_in[6];
    const float* W_r    = (const float*)d_in[7];
    const float* b_r    = (const float*)d_in[8];
    const float* W_s    = (const float*)d_in[9];
    const float* b_s    = (const float*)d_in[10];
    const float* norm_w = (const float*)d_in[11];
    const float* hnw    = (const float*)d_in[12];
    const float* W1     = (const float*)d_in[13];
    const float* b1     = (const float*)d_in[14];
    const float* W2     = (const float*)d_in[15];
    const float* b2     = (const float*)d_in[16];

    char* p = (char*)d_ws;
    uint32* zsb = (uint32*)p;          p += (size_t)BT * 256 * 4;
    bf16* zn_a  = (bf16*)p;            p += (size_t)16 * TPB * 256 * 2;
    bf16* zn_b  = (bf16*)p;            p += (size_t)16 * TPB * 256 * 2;
    bf16* wf0   = (bf16*)p;            p += (size_t)NL * 65536 * 2;
    bf16* wf1   = (bf16*)p;            p += (size_t)NL * 65536 * 2;
    bf16* wg0   = (bf16*)p;            p += (size_t)NL * 65536 * 2;
    bf16* wg1   = (bf16*)p;            p += (size_t)NL * 65536 * 2;
    bf16* wr    = (bf16*)p;            p += (size_t)NL * 65536 * 2;
    bf16* ws    = (bf16*)p;            p += (size_t)NL * 65536 * 2;
    bf16* winb  = (bf16*)p;            p += 65536 * 2;
    bf16* w1b   = (bf16*)p;            p += 262144 * 2;
    bf16* w2b   = (bf16*)p;            p += 131072 * 2;

    zero_pads<<<2048, 256, 0, stream>>>(zn_a, zn_b);
    prep_w2<<<NL * 256, 256, 0, stream>>>(W_f, W_g, wf0, wf1, wg0, wg1);
    prep_w1<<<NL * 256, 256, 0, stream>>>(W_r, W_s, wr, ws);
    prep_misc<<<1792, 256, 0, stream>>>(W_in, W1, W2, winb, w1b, w2b);
    in_conv_kernel<<<BT / 64, 512, 0, stream>>>(x, winb, b_in, norm_w, zsb, zn_a);

    static const int dil[NL] = {1,2,4,8,16,32,64,128,256,512,
                                1,2,4,8,16,32,64,128,256,512};
    for (int i = 0; i < NL; ++i) {
        const bf16* zi = (i & 1) ? zn_b : zn_a;
        bf16* zo_      = (i & 1) ? zn_a : zn_b;
        int mode = (i == NL - 1) ? 2 : 1;
        const float* nw = (i == NL - 1) ? hnw : (norm_w + (size_t)(i + 1) * 256);
        layer_kernel<<<BT / 64, 512, 0, stream>>>(zi, zo_, zsb,
            wf0 + (size_t)i * 65536, wf1 + (size_t)i * 65536,
            wg0 + (size_t)i * 65536, wg1 + (size_t)i * 65536,
            wr + (size_t)i * 65536, ws + (size_t)i * 65536,
            b_f + i * 256, b_g + i * 256, b_r + i * 256, b_s + i * 256,
            nw, dil[i], mode);
    }
    // NL=20 even: last layer wrote zn_a
    head_kernel<<<BT / 64, 512, 0, stream>>>(zn_a, w1b, b1, w2b, b2, (float*)d_out);
}

// Round 10
// 2930.352 us; speedup vs baseline: 1.7774x; 1.7774x over previous
//
#include <hip/hip_runtime.h>
#include <hip/hip_bf16.h>

#define T 4096
#define BT (16*4096)
#define NL 20
#define TPB 4608   // 512 pad + 4096 tokens per batch
#define PAD 512

typedef __bf16 bf16;
typedef __bf16 v8bf __attribute__((ext_vector_type(8)));
typedef float v4f __attribute__((ext_vector_type(4)));
typedef unsigned int uint32;
typedef unsigned short ushort16;

#define MFMA(a,b,c) __builtin_amdgcn_mfma_f32_16x16x32_bf16((a),(b),(c),0,0,0)

__device__ __forceinline__ int swz512(int row, int bc)  { return row*512  + (bc ^ ((row&7)<<4)); }

__device__ __forceinline__ void gload16(const void* g, void* l) {
    __builtin_amdgcn_global_load_lds(
        (const __attribute__((address_space(1))) void*)g,
        (__attribute__((address_space(3))) void*)l, 16, 0, 0);
}

__device__ __forceinline__ ushort16 bfbits(float v) {
    bf16 h = (bf16)v; return *(ushort16*)&h;
}
__device__ __forceinline__ uint32 pack2(float zf, float sf) {
    return (uint32)bfbits(zf) | ((uint32)bfbits(sf) << 16);
}
__device__ __forceinline__ float lo_f(uint32 v) { uint32 t = v << 16;          return *(float*)&t; }
__device__ __forceinline__ float hi_f(uint32 v) { uint32 t = v & 0xffff0000u;  return *(float*)&t; }
__device__ __forceinline__ float sel_f(uint32 pair, int j) {  // j&1: 0=lo,1=hi
    uint32 t = (j & 1) ? (pair & 0xffff0000u) : (pair << 16);
    return *(float*)&t;
}
__device__ __forceinline__ float tanh_clamped(float fv) {
    fv = fminf(fmaxf(fv, -20.f), 20.f);
    float e2 = __expf(-2.f * fv);
    return (1.f - e2) / (1.f + e2);
}
__device__ __forceinline__ float sigmoidf_(float v) {
    return 1.f / (1.f + __expf(-v));
}

// ---------------- zero the per-batch pad stripes of both zn buffers ----------------
__global__ void zero_pads(bf16* __restrict__ zn_a, bf16* __restrict__ zn_b) {
    int idx = blockIdx.x * 256 + threadIdx.x;      // 2*16*16384 uint4
    int buf = idx >> 18;
    int r = idx & 262143;
    int b = r >> 14, off = r & 16383;              // pad = 512 rows * 32 uint4
    bf16* base = buf ? zn_b : zn_a;
    ((uint4*)(base + (size_t)b * TPB * 256))[off] = make_uint4(0, 0, 0, 0);
}

// ---------------- prep kernels: cast/reorder weights to bf16 ----------------
__global__ void prep_w2(const float* __restrict__ Wf, const float* __restrict__ Wg,
                        bf16* __restrict__ wf0, bf16* __restrict__ wf1,
                        bf16* __restrict__ wg0, bf16* __restrict__ wg1) {
    int idx = blockIdx.x * 256 + threadIdx.x;       // NL*256*256
    const float* pf = Wf + (size_t)idx * 2;
    wf0[idx] = (bf16)pf[0]; wf1[idx] = (bf16)pf[1];
    const float* pg = Wg + (size_t)idx * 2;
    wg0[idx] = (bf16)pg[0]; wg1[idx] = (bf16)pg[1];
}

__global__ void prep_w1(const float* __restrict__ Wr, const float* __restrict__ Ws,
                        bf16* __restrict__ wr, bf16* __restrict__ ws) {
    int idx = blockIdx.x * 256 + threadIdx.x;       // NL*256*256
    wr[idx] = (bf16)Wr[idx]; ws[idx] = (bf16)Ws[idx];
}

__global__ void prep_misc(const float* __restrict__ W_in, const float* __restrict__ W1,
                          const float* __restrict__ W2,
                          bf16* __restrict__ winb, bf16* __restrict__ w1b, bf16* __restrict__ w2b) {
    int idx = blockIdx.x * 256 + threadIdx.x;       // 458752 total
    if (idx < 65536) {
        int c = idx >> 8, jj = idx & 255, k = jj >> 3, ci = jj & 7;
        winb[idx] = (bf16)W_in[c * 256 + ci * 32 + k];   // winb[c][k*8+ci]
    } else if (idx < 327680) {
        int j = idx - 65536; w1b[j] = (bf16)W1[j];
    } else {
        int j = idx - 327680; w2b[j] = (bf16)W2[j];
    }
}

// ---------------- fused input conv + RMSNorm(norm_w[0]) ----------------
// 8 waves; wave w owns all 64 rows x cols [w*32, w*32+32)
__global__ __launch_bounds__(512, 4) void in_conv_kernel(
    const float* __restrict__ x, const bf16* __restrict__ winb,
    const float* __restrict__ b_in, const float* __restrict__ nw0,
    uint32* __restrict__ zsb, bf16* __restrict__ znout) {
    __shared__ __align__(16) char smem[65536];
    char* cW  = smem + 32768;                 // window tile
    char* cZn = smem;                         // zn staging
    float* rsq = (float*)(smem + 32768);      // alias cW after GEMM reads
    const int tid = threadIdx.x;
    const int g0 = blockIdx.x * 64;
    const int tl0 = g0 & (T - 1);
    const size_t pr0 = (size_t)(g0 >> 12) * TPB + PAD + tl0;
    for (int i = 0; i < 4; ++i) {
        int ch = tid + i * 512;
        int r = ch >> 5, c16 = ch & 31;
        int tok = tl0 + r - 31 + c16;
        bf16 t8[8] = {};
        if (tok >= 0) {
            const float* xr = x + (size_t)(g0 + r - 31 + c16) * 8;
            float4 xa = ((const float4*)xr)[0];
            float4 xb4 = ((const float4*)xr)[1];
            t8[0]=(bf16)xa.x; t8[1]=(bf16)xa.y; t8[2]=(bf16)xa.z; t8[3]=(bf16)xa.w;
            t8[4]=(bf16)xb4.x; t8[5]=(bf16)xb4.y; t8[6]=(bf16)xb4.z; t8[7]=(bf16)xb4.w;
        }
        *(uint4*)(cW + swz512(r, c16 * 16)) = *(uint4*)t8;
    }
    __syncthreads();
    const int lane = tid & 63, w = tid >> 6;
    const int wn = w;
    const int l15 = lane & 15, l4 = lane >> 4;
    const int cbase = wn * 32 + l15;
    uint32* zb_t = zsb + ((size_t)blockIdx.x * 512 + tid) * 32;

    float p8[4][4] = {};
    uint32 zpk[2][4][2] = {};
    #pragma unroll
    for (int half = 0; half < 2; ++half) {
        v4f acc[4] = {};
        __builtin_amdgcn_s_setprio(1);
        #pragma unroll
        for (int ks = 0; ks < 8; ++ks) {
            v8bf b = *(const v8bf*)(winb + (size_t)(cbase + half*16)*256 + ks*32 + l4*8);
            #pragma unroll
            for (int m = 0; m < 4; ++m) {
                v8bf a = *(const v8bf*)(cW + swz512(m*16 + l15, ks*64 + l4*16));
                acc[m] = MFMA(a, b, acc[m]);
            }
        }
        __builtin_amdgcn_s_setprio(0);
        float bv = b_in[cbase + half*16];
        #pragma unroll
        for (int m = 0; m < 4; ++m) {
            uint32 st[4];
            #pragma unroll
            for (int j = 0; j < 4; ++j) {
                float zf = acc[m][j] + bv;
                st[j] = pack2(zf, 0.f);
                p8[m][j] += zf * zf;
                zpk[half][m][j>>1] |= (uint32)bfbits(zf) << ((j&1)*16);
            }
            *(uint4*)(zb_t + half*16 + m*4) = make_uint4(st[0], st[1], st[2], st[3]);
        }
    }
    __syncthreads();                                  // window reads done
    #pragma unroll
    for (int m = 0; m < 4; ++m)
        #pragma unroll
        for (int j = 0; j < 4; ++j) {
            float p = p8[m][j];
            p += __shfl_xor(p,1); p += __shfl_xor(p,2); p += __shfl_xor(p,4); p += __shfl_xor(p,8);
            if (l15 == 0) rsq[(m*16 + l4*4 + j)*9 + wn] = p;
        }
    __syncthreads();                                  // rsq ready
    #pragma unroll
    for (int m = 0; m < 4; ++m)
        #pragma unroll
        for (int j = 0; j < 4; ++j) {
            int row = m*16 + l4*4 + j;
            const float* rr = rsq + row*9;
            float s8 = rr[0]+rr[1]+rr[2]+rr[3]+rr[4]+rr[5]+rr[6]+rr[7];
            float iv = rsqrtf(s8*(1.f/256.f) + 1e-6f);
            #pragma unroll
            for (int half = 0; half < 2; ++half) {
                int col = cbase + half*16;
                float zf = sel_f(zpk[half][m][j>>1], j);
                *(bf16*)(cZn + swz512(row, col*2)) = (bf16)(zf * iv * nw0[col]);
            }
        }
    __syncthreads();
    #pragma unroll
    for (int k = 0; k < 4; ++k) {
        int idx = tid + k * 512;
        int row = idx >> 5, d = idx & 31;
        uint4 v = *(uint4*)(cZn + swz512(row, d*16));
        *((uint4*)(znout + (pr0 + row) * 256) + d) = v;
    }
}

// ---------------- fused gated-residual layer + next-layer RMSNorm ----------------
// wave w owns all 64 rows x cols [w*32, w*32+32). mode: 1=normal, 2=last
__global__ __launch_bounds__(512, 4) void layer_kernel(
    const bf16* __restrict__ znin, bf16* __restrict__ znout, uint32* __restrict__ zsb,
    const bf16* __restrict__ wf0, const bf16* __restrict__ wf1,
    const bf16* __restrict__ wg0, const bf16* __restrict__ wg1,
    const bf16* __restrict__ wr, const bf16* __restrict__ wsm,
    const float* __restrict__ bfp, const float* __restrict__ bgp,
    const float* __restrict__ brp, const float* __restrict__ bsp,
    const float* __restrict__ nw, int dil, int mode) {
    __shared__ __align__(16) char smem[65536];
    char* cA0 = smem;                     // zn[t-d] tile -> U tile -> zn-out staging
    char* cA1 = smem + 32768;             // zn[t] tile
    float* rsq = (float*)(smem + 32768);  // alias cA1 (dead after GEMM1)
    const int tid = threadIdx.x;
    const int lane = tid & 63, w = tid >> 6;
    const int g0 = blockIdx.x * 64;
    const size_t pr0 = (size_t)(g0 >> 12) * TPB + PAD + (g0 & (T - 1));

    // async stage zn[t]->cA1, zn[t-dil]->cA0 with pre-swizzled global source
    {
        int rl = w * 8 + (lane >> 5);
        int d = lane & 31;
        #pragma unroll
        for (int j = 0; j < 4; ++j) {
            int r = rl + j * 2;
            int s = d ^ (r & 7);
            gload16(znin + (pr0 + r) * 256 + s * 8,       cA1 + (w*8 + j*2) * 512);
            gload16(znin + (pr0 + r - dil) * 256 + s * 8, cA0 + (w*8 + j*2) * 512);
        }
    }

    const int wn = w;
    const int l15 = lane & 15, l4 = lane >> 4;
    const int cbase = wn * 32 + l15;
    uint32* zb_t = zsb + ((size_t)blockIdx.x * 512 + tid) * 32;

    __syncthreads();                               // S1

    // prefetch zsb old (half 0) — latency hides under GEMM1
    uint4 old0[4];
    #pragma unroll
    for (int m = 0; m < 4; ++m) old0[m] = *(const uint4*)(zb_t + m*4);

    // ---- GEMM1: f+g combined, per 16-col half ----
    uint32 upk[2][4][2];                           // [half][m][jpair] packed bf16 u
    #pragma unroll
    for (int half = 0; half < 2; ++half) {
        v4f accf[4] = {}, accg[4] = {};
        __builtin_amdgcn_s_setprio(1);
        #pragma unroll
        for (int ks = 0; ks < 8; ++ks) {
            size_t bo = (size_t)(cbase + half*16) * 256 + ks*32 + l4*8;
            v8bf bf0 = *(const v8bf*)(wf0 + bo);
            v8bf bf1 = *(const v8bf*)(wf1 + bo);
            v8bf bg0 = *(const v8bf*)(wg0 + bo);
            v8bf bg1 = *(const v8bf*)(wg1 + bo);
            #pragma unroll
            for (int m = 0; m < 4; ++m) {
                int off = swz512(m*16 + l15, ks*64 + l4*16);
                v8bf a0 = *(const v8bf*)(cA0 + off);
                v8bf a1 = *(const v8bf*)(cA1 + off);
                accf[m] = MFMA(a0, bf0, accf[m]);
                accf[m] = MFMA(a1, bf1, accf[m]);
                accg[m] = MFMA(a0, bg0, accg[m]);
                accg[m] = MFMA(a1, bg1, accg[m]);
            }
        }
        __builtin_amdgcn_s_setprio(0);
        float bfv = bfp[cbase + half*16];
        float bgv = bgp[cbase + half*16];
        #pragma unroll
        for (int m = 0; m < 4; ++m)
            #pragma unroll
            for (int jp = 0; jp < 2; ++jp) {
                float u0 = tanh_clamped(accf[m][jp*2]   + bfv) * sigmoidf_(accg[m][jp*2]   + bgv);
                float u1 = tanh_clamped(accf[m][jp*2+1] + bfv) * sigmoidf_(accg[m][jp*2+1] + bgv);
                upk[half][m][jp] = (uint32)bfbits(u0) | ((uint32)bfbits(u1) << 16);
            }
    }
    __syncthreads();                               // S2: all GEMM1 tile reads done

    // write U tile (bf16, swizzled) into cA0
    #pragma unroll
    for (int half = 0; half < 2; ++half)
        #pragma unroll
        for (int m = 0; m < 4; ++m) {
            int col = cbase + half*16;
            #pragma unroll
            for (int j = 0; j < 4; ++j) {
                int row = m*16 + l4*4 + j;
                *(bf16*)(cA0 + swz512(row, col*2)) = (bf16)sel_f(upk[half][m][j>>1], j);
            }
        }
    __syncthreads();                               // S3

    // prefetch zsb old (half 1) — hides under GEMM2 half0
    uint4 old1[4];
    #pragma unroll
    for (int m = 0; m < 4; ++m) old1[m] = *(const uint4*)(zb_t + 16 + m*4);

    // ---- GEMM2 per half with blocked zs RMW ----
    uint32 zpk[2][4][2] = {};
    #pragma unroll
    for (int half = 0; half < 2; ++half) {
        v4f accr[4] = {}, accs[4] = {};
        if (mode != 2) {
            __builtin_amdgcn_s_setprio(1);
            #pragma unroll
            for (int ks = 0; ks < 8; ++ks) {
                size_t bo = (size_t)(cbase + half*16) * 256 + ks*32 + l4*8;
                v8bf br_ = *(const v8bf*)(wr + bo);
                v8bf bs_ = *(const v8bf*)(wsm + bo);
                #pragma unroll
                for (int m = 0; m < 4; ++m) {
                    v8bf a = *(const v8bf*)(cA0 + swz512(m*16 + l15, ks*64 + l4*16));
                    accr[m] = MFMA(a, br_, accr[m]);
                    accs[m] = MFMA(a, bs_, accs[m]);
                }
            }
            __builtin_amdgcn_s_setprio(0);
        } else {
            __builtin_amdgcn_s_setprio(1);
            #pragma unroll
            for (int ks = 0; ks < 8; ++ks) {
                size_t bo = (size_t)(cbase + half*16) * 256 + ks*32 + l4*8;
                v8bf bs_ = *(const v8bf*)(wsm + bo);
                #pragma unroll
                for (int m = 0; m < 4; ++m) {
                    v8bf a = *(const v8bf*)(cA0 + swz512(m*16 + l15, ks*64 + l4*16));
                    accs[m] = MFMA(a, bs_, accs[m]);
                }
            }
            __builtin_amdgcn_s_setprio(0);
        }
        if (mode != 2) {
            float brv = brp[cbase + half*16];
            float bsv = bsp[cbase + half*16];
            #pragma unroll
            for (int m = 0; m < 4; ++m) {
                uint4 o4 = half ? old1[m] : old0[m];
                uint32 old_[4] = {o4.x, o4.y, o4.z, o4.w};
                uint32 st[4];
                #pragma unroll
                for (int j = 0; j < 4; ++j) {
                    float zf = lo_f(old_[j]) + accr[m][j] + brv;
                    float sf = hi_f(old_[j]) + accs[m][j] + bsv;
                    st[j] = pack2(zf, sf);
                    zpk[half][m][j>>1] |= (uint32)bfbits(zf) << ((j&1)*16);
                }
                *(uint4*)(zb_t + half*16 + m*4) = make_uint4(st[0], st[1], st[2], st[3]);
            }
        } else {
            float bsv = bsp[cbase + half*16];
            #pragma unroll
            for (int m = 0; m < 4; ++m) {
                uint4 o4 = half ? old1[m] : old0[m];
                uint32 old_[4] = {o4.x, o4.y, o4.z, o4.w};
                #pragma unroll
                for (int j = 0; j < 4; ++j) {
                    float of = fmaxf(hi_f(old_[j]) + accs[m][j] + bsv, 0.f);
                    zpk[half][m][j>>1] |= (uint32)bfbits(of) << ((j&1)*16);
                }
            }
        }
    }
    // rsq partials from packed bf16 z values (saves 16 live regs across GEMM2)
    #pragma unroll
    for (int m = 0; m < 4; ++m)
        #pragma unroll
        for (int j = 0; j < 4; ++j) {
            float z0 = sel_f(zpk[0][m][j>>1], j);
            float z1 = sel_f(zpk[1][m][j>>1], j);
            float p = z0*z0 + z1*z1;
            p += __shfl_xor(p,1); p += __shfl_xor(p,2); p += __shfl_xor(p,4); p += __shfl_xor(p,8);
            if (l15 == 0) rsq[(m*16 + l4*4 + j)*9 + wn] = p;
        }
    __syncthreads();                               // S4: GEMM2 reads + rsq done

    // zn staging (bf16, swizzled) into cA0
    #pragma unroll
    for (int m = 0; m < 4; ++m)
        #pragma unroll
        for (int j = 0; j < 4; ++j) {
            int row = m*16 + l4*4 + j;
            const float* rr = rsq + row*9;
            float s8 = rr[0]+rr[1]+rr[2]+rr[3]+rr[4]+rr[5]+rr[6]+rr[7];
            float iv = rsqrtf(s8*(1.f/256.f) + 1e-6f);
            #pragma unroll
            for (int half = 0; half < 2; ++half) {
                int col = cbase + half*16;
                float zf = sel_f(zpk[half][m][j>>1], j);
                *(bf16*)(cA0 + swz512(row, col*2)) = (bf16)(zf * iv * nw[col]);
            }
        }
    __syncthreads();                               // S5

    // coalesced zn copyout (padded layout)
    #pragma unroll
    for (int k = 0; k < 4; ++k) {
        int idx = tid + k * 512;
        int row = idx >> 5, d = idx & 31;
        uint4 v = *(uint4*)(cA0 + swz512(row, d*16));
        *((uint4*)(znout + (pr0 + row) * 256) + d) = v;
    }
}

// ---------------- fused head: on @ W1 -> relu -> @ W2 (8 waves, dedup'd cols) ----------------
__global__ __launch_bounds__(512, 4) void head_kernel(
    const bf16* __restrict__ on, const bf16* __restrict__ w1b, const float* __restrict__ b1,
    const bf16* __restrict__ w2b, const float* __restrict__ b2, float* __restrict__ out) {
    __shared__ __align__(16) char smem[65536];
    char* cOn = smem;
    char* cH  = smem + 32768;
    const int tid = threadIdx.x;
    const int g0 = blockIdx.x * 64;
    const size_t pr0 = (size_t)(g0 >> 12) * TPB + PAD + (g0 & (T - 1));
    for (int i = 0; i < 4; ++i) {
        int ch = tid + i * 512;
        int r = ch >> 5, c16 = ch & 31;
        *(uint4*)(cOn + swz512(r, c16 * 16)) = *((const uint4*)(on + (pr0 + r) * 256) + c16);
    }
    __syncthreads();
    const int lane = tid & 63, w = tid >> 6;
    const int l15 = lane & 15, l4 = lane >> 4;
    v4f acc2[4] = {};                       // out cols [w*16, w*16+16), all 64 rows
    for (int hc = 0; hc < 4; ++hc) {
        // GEMM1: wave w computes H cols hc*256 + w*32 + {0,16}+l15, all 64 rows
        v4f acch[4][2] = {};
        __builtin_amdgcn_s_setprio(1);
        #pragma unroll
        for (int ks = 0; ks < 8; ++ks) {
            v8bf b0 = *(const v8bf*)(w1b + (size_t)(hc*256 + w*32 + l15) * 256 + ks*32 + l4*8);
            v8bf b1v_ = *(const v8bf*)(w1b + (size_t)(hc*256 + w*32 + 16 + l15) * 256 + ks*32 + l4*8);
            #pragma unroll
            for (int m = 0; m < 4; ++m) {
                v8bf a = *(const v8bf*)(cOn + swz512(m*16 + l15, ks*64 + l4*16));
                acch[m][0] = MFMA(a, b0, acch[m][0]);
                acch[m][1] = MFMA(a, b1v_, acch[m][1]);
            }
        }
        __builtin_amdgcn_s_setprio(0);
        __syncthreads();   // previous hc's cH reads done
        #pragma unroll
        for (int m = 0; m < 4; ++m)
            #pragma unroll
            for (int nh = 0; nh < 2; ++nh) {
                int coll = w*32 + nh*16 + l15;
                float b1v = b1[hc * 256 + coll];
                #pragma unroll
                for (int j = 0; j < 4; ++j) {
                    int row = m*16 + l4*4 + j;
                    float hv = fmaxf(acch[m][nh][j] + b1v, 0.f);
                    *(bf16*)(cH + swz512(row, coll * 2)) = (bf16)hv;
                }
            }
        __syncthreads();
        // GEMM2: wave w accumulates out cols w*16+l15 over this hc chunk (K=256)
        __builtin_amdgcn_s_setprio(1);
        #pragma unroll
        for (int ks = 0; ks < 8; ++ks) {
            v8bf b = *(const v8bf*)(w2b + (size_t)(w*16 + l15) * 1024 + hc * 256 + ks * 32 + l4 * 8);
            #pragma unroll
            for (int m = 0; m < 4; ++m) {
                v8bf a = *(const v8bf*)(cH + swz512(m*16 + l15, ks*64 + l4*16));
                acc2[m] = MFMA(a, b, acc2[m]);
            }
        }
        __builtin_amdgcn_s_setprio(0);
    }
    {
        int o = w*16 + l15;
        float b2v = b2[o];
        #pragma unroll
        for (int m = 0; m < 4; ++m)
            #pragma unroll
            for (int j = 0; j < 4; ++j) {
                int row = m*16 + l4*4 + j;
                out[(size_t)(g0 + row) * 128 + o] = acc2[m][j] + b2v;
            }
    }
}

extern "C" void kernel_launch(void* const* d_in, const int* in_sizes, int n_in,
                              void* d_out, int out_size, void* d_ws, size_t ws_size,
                              hipStream_t stream) {
    const float* x      = (const float*)d_in[0];
    const float* W_in   = (const float*)d_in[1];
    const float* b_in   = (const float*)d_in[2];
    const float* W_f    = (const float*)d_in[3];
    const float* b_f    = (const float*)d_in[4];
    const float* W_g    = (const float*)d_in[5];
    const float* b_g    = (const float*)d_in[6];
    const float* W_r    = (const float*)d_in[7];
    const float* b_r    = (const float*)d_in[8];
    const float* W_s    = (const float*)d_in[9];
    const float* b_s    = (const float*)d_in[10];
    const float* norm_w = (const float*)d_in[11];
    const float* hnw    = (const float*)d_in[12];
    const float* W1     = (const float*)d_in[13];
    const float* b1     = (const float*)d_in[14];
    const float* W2     = (const float*)d_in[15];
    const float* b2     = (const float*)d_in[16];

    char* p = (char*)d_ws;
    uint32* zsb = (uint32*)p;          p += (size_t)BT * 256 * 4;
    bf16* zn_a  = (bf16*)p;            p += (size_t)16 * TPB * 256 * 2;
    bf16* zn_b  = (bf16*)p;            p += (size_t)16 * TPB * 256 * 2;
    bf16* wf0   = (bf16*)p;            p += (size_t)NL * 65536 * 2;
    bf16* wf1   = (bf16*)p;            p += (size_t)NL * 65536 * 2;
    bf16* wg0   = (bf16*)p;            p += (size_t)NL * 65536 * 2;
    bf16* wg1   = (bf16*)p;            p += (size_t)NL * 65536 * 2;
    bf16* wr    = (bf16*)p;            p += (size_t)NL * 65536 * 2;
    bf16* ws    = (bf16*)p;            p += (size_t)NL * 65536 * 2;
    bf16* winb  = (bf16*)p;            p += 65536 * 2;
    bf16* w1b   = (bf16*)p;            p += 262144 * 2;
    bf16* w2b   = (bf16*)p;            p += 131072 * 2;

    zero_pads<<<2048, 256, 0, stream>>>(zn_a, zn_b);
    prep_w2<<<NL * 256, 256, 0, stream>>>(W_f, W_g, wf0, wf1, wg0, wg1);
    prep_w1<<<NL * 256, 256, 0, stream>>>(W_r, W_s, wr, ws);
    prep_misc<<<1792, 256, 0, stream>>>(W_in, W1, W2, winb, w1b, w2b);
    in_conv_kernel<<<BT / 64, 512, 0, stream>>>(x, winb, b_in, norm_w, zsb, zn_a);

    static const int dil[NL] = {1,2,4,8,16,32,64,128,256,512,
                                1,2,4,8,16,32,64,128,256,512};
    for (int i = 0; i < NL; ++i) {
        const bf16* zi = (i & 1) ? zn_b : zn_a;
        bf16* zo_      = (i & 1) ? zn_a : zn_b;
        int mode = (i == NL - 1) ? 2 : 1;
        const float* nw = (i == NL - 1) ? hnw : (norm_w + (size_t)(i + 1) * 256);
        layer_kernel<<<BT / 64, 512, 0, stream>>>(zi, zo_, zsb,
            wf0 + (size_t)i * 65536, wf1 + (size_t)i * 65536,
            wg0 + (size_t)i * 65536, wg1 + (size_t)i * 65536,
            wr + (size_t)i * 65536, ws + (size_t)i * 65536,
            b_f + i * 256, b_g + i * 256, b_r + i * 256, b_s + i * 256,
            nw, dil[i], mode);
    }
    // NL=20 even: last layer wrote zn_a
    head_kernel<<<BT / 64, 512, 0, stream>>>(zn_a, w1b, b1, w2b, b2, (float*)d_out);
}